// Round 7
// baseline (295.485 us; speedup 1.0000x reference)
//
#include <hip/hip_runtime.h>
#include <hip/hip_bf16.h>
#include <cstdint>
#include <cstddef>

// B=1, T=2048, D=1024, E=8, F=2048, K=2. fp32 in/out; bf16 MFMA internally.
#define N_TOK 2048
#define DIM   1024
#define NEXP  8
#define FDIM  2048

#define BM 128
#define BN 128
#define BK 64

typedef __attribute__((ext_vector_type(8))) short short8;   // 8 x bf16
typedef __attribute__((ext_vector_type(4))) float f32x4;    // MFMA C/D
typedef unsigned short ushort_t;

// ---- workspace layout (bytes) ----
#define OFF_COUNTS  0
#define OFF_TOK     4096
#define OFF_GATE    (OFF_TOK + NEXP * N_TOK * 4)
#define OFF_A       ((size_t)1 << 20)                              // Abuf bf16: 4096x2048x2 = 16 MiB
#define OFF_W1B     (OFF_A  + (size_t)2 * N_TOK * FDIM * 2)        // W1 bf16: 32 MiB
#define OFF_W2B     (OFF_W1B + (size_t)NEXP * FDIM * DIM * 2)      // W2 bf16: 32 MiB
#define OFF_XB      (OFF_W2B + (size_t)NEXP * DIM * FDIM * 2)      // x bf16: 4 MiB
// total ~85.1 MiB

__device__ __forceinline__ uint32_t cvt2(float lo, float hi) {
  __hip_bfloat162 p = __float22bfloat162_rn(make_float2(lo, hi));
  uint32_t r; __builtin_memcpy(&r, &p, 4); return r;
}

// async global->LDS, 16B per lane; LDS dest is wave-uniform base + lane*16
__device__ __forceinline__ void gl16(const ushort_t* g, const ushort_t* l) {
  __builtin_amdgcn_global_load_lds(
      (const __attribute__((address_space(1))) void*)g,
      (__attribute__((address_space(3))) void*)l, 16, 0, 0);
}

// bijective XCD-chunked swizzle (m204): consecutive dispatch ids round-robin
// XCDs; remap so each XCD owns a contiguous chunk of logical blocks.
__device__ __forceinline__ int xcd_swz(int bid, int nwg) {
  int q = nwg >> 3, r = nwg & 7;
  int xcd = bid & 7, local = bid >> 3;
  int base = (xcd < r) ? xcd * (q + 1) : r * (q + 1) + (xcd - r) * q;
  return base + local;
}

// ---------------- prep: fp32 -> bf16 (exact-fit partition, 64 elem/thread) ----------------
// blocks [0,1024) -> W1 (16.8M elems), [1024,2048) -> W2, [2048,2176) -> x (2.1M)
__global__ __launch_bounds__(256) void prep_kernel(
    const float* __restrict__ W1, const float* __restrict__ W2, const float* __restrict__ x,
    ushort_t* __restrict__ W1b, ushort_t* __restrict__ W2b, ushort_t* __restrict__ xb) {
  int b = blockIdx.x;
  const float* s; ushort_t* d; size_t off;
  if (b < 1024)      { s = W1; d = W1b; off = (size_t)b * 16384; }
  else if (b < 2048) { s = W2; d = W2b; off = (size_t)(b - 1024) * 16384; }
  else               { s = x;  d = xb;  off = (size_t)(b - 2048) * 16384; }
  s += off; d += off;
  int t8 = threadIdx.x * 8;
#pragma unroll
  for (int j = 0; j < 8; ++j) {
    float4 f0 = *(const float4*)(s + j * 2048 + t8);
    float4 f1 = *(const float4*)(s + j * 2048 + t8 + 4);
    *(uint4*)(d + j * 2048 + t8) =
        make_uint4(cvt2(f0.x, f0.y), cvt2(f0.z, f0.w), cvt2(f1.x, f1.y), cvt2(f1.z, f1.w));
  }
}

// ---------------- router: 4 waves/block, 1 wave per token (fp32, exact) ----------------
__global__ __launch_bounds__(256) void router_kernel(
    const float* __restrict__ x, const float* __restrict__ Wr,
    int* __restrict__ counts, int* __restrict__ toklist,
    float* __restrict__ gatelist) {
  int n = blockIdx.x * 4 + (threadIdx.x >> 6);
  int lane = threadIdx.x & 63;
  const float* xr = x + (size_t)n * DIM;

  float xv[DIM / 64];
#pragma unroll
  for (int i = 0; i < DIM / 64; ++i) xv[i] = xr[lane + 64 * i];

  float logit[NEXP];
#pragma unroll
  for (int e = 0; e < NEXP; ++e) {
    const float* wr = Wr + (size_t)e * DIM;
    float s = 0.f;
#pragma unroll
    for (int i = 0; i < DIM / 64; ++i) s += xv[i] * wr[lane + 64 * i];
#pragma unroll
    for (int off = 32; off; off >>= 1) s += __shfl_down(s, off);
    logit[e] = s;
  }

  if (lane == 0) {
    float m = logit[0];
#pragma unroll
    for (int e = 1; e < NEXP; ++e) m = fmaxf(m, logit[e]);
    float p[NEXP];
#pragma unroll
    for (int e = 0; e < NEXP; ++e) p[e] = expf(logit[e] - m);
    int i1 = 0;
#pragma unroll
    for (int e = 1; e < NEXP; ++e) if (p[e] > p[i1]) i1 = e;
    int i2 = (i1 == 0) ? 1 : 0;
#pragma unroll
    for (int e = 0; e < NEXP; ++e)
      if (e != i1 && p[e] > p[i2]) i2 = e;
    float denom = p[i1] + p[i2];

    int pos1 = atomicAdd(&counts[i1], 1);
    toklist[i1 * N_TOK + pos1] = n;
    gatelist[i1 * N_TOK + pos1] = p[i1] / denom;

    int pos2 = atomicAdd(&counts[i2], 1);
    toklist[i2 * N_TOK + pos2] = n;
    gatelist[i2 * N_TOK + pos2] = p[i2] / denom;
  }
}

// ---------------- fc1: Abuf[base+r, f] = relu(xb[tok[r],:] . W1b[e,f,:])^2 ----------------
// m97 structure: 128x128x64 tile, single 32KB LDS buffer, global_load_lds staging,
// source-side XOR swizzle (col16 ^= row&7), 4 waves 2x2, 3 blocks/CU.
__global__ __launch_bounds__(256, 3) void fc1_mfma(
    const ushort_t* __restrict__ xb, const ushort_t* __restrict__ W1b,
    const int* __restrict__ counts, const int* __restrict__ toklist,
    __hip_bfloat16* __restrict__ Abuf) {
  const int ROWB = N_TOK / BM;     // 16
  const int COLB = FDIM / BN;      // 16
  int bid = xcd_swz(blockIdx.x, NEXP * ROWB * COLB);  // chunk = 256 = one expert per XCD
  int e  = bid / (ROWB * COLB);
  int rb = (bid / COLB) % ROWB;
  int cb = bid % COLB;
  int ne = counts[e];
  if (rb * BM >= ne) return;
  int base = 0;
  for (int i = 0; i < e; ++i) base += counts[i];

  __shared__ ushort_t As[BM * BK];   // 16 KiB
  __shared__ ushort_t Bs[BN * BK];   // 16 KiB

  int tid = threadIdx.x, lane = tid & 63, w = tid >> 6;

  // gload addressing: LDS slot (w,i,lane) covers row = w*32+i*8+(lane>>3), col16 = lane&7.
  // Source fetches col16 ^ (row&7) so swizzled reads below see linear data.
  const ushort_t* gA[4]; const ushort_t* gB[4];
  const ushort_t* lA[4]; const ushort_t* lB[4];
#pragma unroll
  for (int i = 0; i < 4; ++i) {
    int row = w * 32 + i * 8 + (lane >> 3);
    int c16 = (lane & 7) ^ (row & 7);
    int r = rb * BM + row; if (r >= ne) r = ne - 1;
    int tok = toklist[e * N_TOK + r];
    gA[i] = xb + (size_t)tok * DIM + c16 * 8;
    gB[i] = W1b + ((size_t)e * FDIM + cb * BN + row) * DIM + c16 * 8;
    lA[i] = &As[w * 2048 + i * 512];
    lB[i] = &Bs[w * 2048 + i * 512];
  }

  int wr = (w >> 1) * 64, wc = (w & 1) * 64;
  int lr = lane & 15, lg = lane >> 4;
  f32x4 acc[4][4] = {};

  for (int t = 0; t < DIM / BK; ++t) {
    __syncthreads();   // prev tile fully consumed
#pragma unroll
    for (int i = 0; i < 4; ++i) {
      gl16(gA[i], lA[i]); gl16(gB[i], lB[i]);
      gA[i] += BK; gB[i] += BK;
    }
    __syncthreads();   // compiler drains vmcnt(0) before barrier -> tile ready
#pragma unroll
    for (int ks = 0; ks < 2; ++ks) {
      short8 af[4], bf[4];
#pragma unroll
      for (int m = 0; m < 4; ++m) {
        int row = wr + m * 16 + lr;
        af[m] = *(const short8*)&As[row * BK + (((ks * 4 + lg) ^ (row & 7)) * 8)];
      }
#pragma unroll
      for (int n = 0; n < 4; ++n) {
        int row = wc + n * 16 + lr;
        bf[n] = *(const short8*)&Bs[row * BK + (((ks * 4 + lg) ^ (row & 7)) * 8)];
      }
#pragma unroll
      for (int m = 0; m < 4; ++m)
#pragma unroll
        for (int n = 0; n < 4; ++n)
          acc[m][n] = __builtin_amdgcn_mfma_f32_16x16x32_bf16(af[m], bf[n], acc[m][n], 0, 0, 0);
    }
  }

  int colbase = cb * BN + wc + lr;
#pragma unroll
  for (int m = 0; m < 4; ++m) {
#pragma unroll
    for (int j = 0; j < 4; ++j) {
      int r = rb * BM + wr + m * 16 + lg * 4 + j;
      if (r < ne) {
        __hip_bfloat16* orow = Abuf + (size_t)(base + r) * FDIM + colbase;
#pragma unroll
        for (int n = 0; n < 4; ++n) {
          float v = fmaxf(acc[m][n][j], 0.f);
          orow[n * 16] = __float2bfloat16(v * v);
        }
      }
    }
  }
}

// ---------------- fc2 (split-K x2): out[tok,d] += g * (Abuf[base+r, ks0:+1024] . W2b[e,d,ks0:]) ----------------
__global__ __launch_bounds__(256, 3) void fc2_mfma(
    const ushort_t* __restrict__ Abuf, const ushort_t* __restrict__ W2b,
    const int* __restrict__ counts, const int* __restrict__ toklist,
    const float* __restrict__ gatelist, float* __restrict__ out) {
  const int ROWB = N_TOK / BM;     // 16
  const int COLB = DIM / BN;       // 8
  int bid = xcd_swz(blockIdx.x, NEXP * ROWB * COLB);  // chunk = 128 = one expert per XCD
  int e  = bid / (ROWB * COLB);
  int rb = (bid / COLB) % ROWB;
  int cb = bid % COLB;
  int ks0 = blockIdx.y * (FDIM / 2);   // 0 or 1024
  int ne = counts[e];
  if (rb * BM >= ne) return;
  int base = 0;
  for (int i = 0; i < e; ++i) base += counts[i];

  __shared__ ushort_t As[BM * BK];
  __shared__ ushort_t Bs[BN * BK];

  int tid = threadIdx.x, lane = tid & 63, w = tid >> 6;

  const ushort_t* gA[4]; const ushort_t* gB[4];
  const ushort_t* lA[4]; const ushort_t* lB[4];
#pragma unroll
  for (int i = 0; i < 4; ++i) {
    int row = w * 32 + i * 8 + (lane >> 3);
    int c16 = (lane & 7) ^ (row & 7);
    int r = rb * BM + row; if (r >= ne) r = ne - 1;
    gA[i] = Abuf + (size_t)(base + r) * FDIM + ks0 + c16 * 8;
    gB[i] = W2b + ((size_t)e * DIM + cb * BN + row) * FDIM + ks0 + c16 * 8;
    lA[i] = &As[w * 2048 + i * 512];
    lB[i] = &Bs[w * 2048 + i * 512];
  }

  int wr = (w >> 1) * 64, wc = (w & 1) * 64;
  int lr = lane & 15, lg = lane >> 4;
  f32x4 acc[4][4] = {};

  for (int t = 0; t < (FDIM / 2) / BK; ++t) {
    __syncthreads();
#pragma unroll
    for (int i = 0; i < 4; ++i) {
      gl16(gA[i], lA[i]); gl16(gB[i], lB[i]);
      gA[i] += BK; gB[i] += BK;
    }
    __syncthreads();
#pragma unroll
    for (int ks = 0; ks < 2; ++ks) {
      short8 af[4], bf[4];
#pragma unroll
      for (int m = 0; m < 4; ++m) {
        int row = wr + m * 16 + lr;
        af[m] = *(const short8*)&As[row * BK + (((ks * 4 + lg) ^ (row & 7)) * 8)];
      }
#pragma unroll
      for (int n = 0; n < 4; ++n) {
        int row = wc + n * 16 + lr;
        bf[n] = *(const short8*)&Bs[row * BK + (((ks * 4 + lg) ^ (row & 7)) * 8)];
      }
#pragma unroll
      for (int m = 0; m < 4; ++m)
#pragma unroll
        for (int n = 0; n < 4; ++n)
          acc[m][n] = __builtin_amdgcn_mfma_f32_16x16x32_bf16(af[m], bf[n], acc[m][n], 0, 0, 0);
    }
  }

  // epilogue: gated atomic accumulate into out (out pre-zeroed)
  int colbase = cb * BN + wc + lr;
#pragma unroll
  for (int m = 0; m < 4; ++m) {
#pragma unroll
    for (int j = 0; j < 4; ++j) {
      int r = rb * BM + wr + m * 16 + lg * 4 + j;
      if (r < ne) {
        int tok = toklist[e * N_TOK + r];
        float g = gatelist[e * N_TOK + r];
        float* orow = out + (size_t)tok * DIM + colbase;
#pragma unroll
        for (int n = 0; n < 4; ++n)
          atomicAdd(&orow[n * 16], g * acc[m][n][j]);
      }
    }
  }
}

extern "C" void kernel_launch(void* const* d_in, const int* in_sizes, int n_in,
                              void* d_out, int out_size, void* d_ws, size_t ws_size,
                              hipStream_t stream) {
  const float* x  = (const float*)d_in[0];
  const float* Wr = (const float*)d_in[1];
  const float* W1 = (const float*)d_in[2];
  const float* W2 = (const float*)d_in[3];
  float* out = (float*)d_out;

  char* ws = (char*)d_ws;
  int*   counts   = (int*)(ws + OFF_COUNTS);
  int*   toklist  = (int*)(ws + OFF_TOK);
  float* gatelist = (float*)(ws + OFF_GATE);
  __hip_bfloat16* Abuf = (__hip_bfloat16*)(ws + OFF_A);
  ushort_t* W1b = (ushort_t*)(ws + OFF_W1B);
  ushort_t* W2b = (ushort_t*)(ws + OFF_W2B);
  ushort_t* xb  = (ushort_t*)(ws + OFF_XB);

  (void)hipMemsetAsync(counts, 0, NEXP * sizeof(int), stream);
  (void)hipMemsetAsync(out, 0, (size_t)out_size * sizeof(float), stream);

  prep_kernel<<<2176, 256, 0, stream>>>(W1, W2, x, W1b, W2b, xb);

  router_kernel<<<N_TOK / 4, 256, 0, stream>>>(x, Wr, counts, toklist, gatelist);

  fc1_mfma<<<NEXP * (N_TOK / BM) * (FDIM / BN), 256, 0, stream>>>(
      xb, W1b, counts, toklist, Abuf);

  fc2_mfma<<<dim3(NEXP * (N_TOK / BM) * (DIM / BN), 2), 256, 0, stream>>>(
      (const ushort_t*)Abuf, W2b, counts, toklist, gatelist, out);
}